// Round 1
// baseline (1586.027 us; speedup 1.0000x reference)
//
#include <hip/hip_runtime.h>
#include <cstdint>

#define HW 25600
#define WIDTH 160
#define NB 8
#define DIM 192
#define CH2 384
#define PCH 288
#define HID 96
#define PROW 176
#define PPS 29216          // 166*176 padded plane
#define OUTN 39321600      // 8*192*25600

typedef short bf16x8 __attribute__((ext_vector_type(8)));
typedef float f32x4 __attribute__((ext_vector_type(4)));

__device__ __forceinline__ unsigned short f2bf(float f) {
  union { float f; unsigned int u; } v; v.f = f;
  unsigned int u = v.u;
  u += 0x7FFFu + ((u >> 16) & 1u);
  return (unsigned short)(u >> 16);
}
__device__ __forceinline__ float bf2f(unsigned int bits16) {
  union { unsigned int u; float f; } v; v.u = bits16 << 16;
  return v.f;
}

// ---------------- K1: per-(b,c) avg & max over 25600 pixels ----------------
__global__ void k_reduce(const float* __restrict__ x1, const float* __restrict__ x2,
                         float* __restrict__ redavg, float* __restrict__ redmax) {
  int bid = blockIdx.x;                 // b*384 + c
  int b = bid / CH2, c = bid % CH2;
  const float* base = (c < DIM) ? (x1 + ((size_t)b * DIM + c) * HW)
                                : (x2 + ((size_t)b * DIM + (c - DIM)) * HW);
  int tid = threadIdx.x;
  float s = 0.f, m = -3.4e38f;
  for (int i = 0; i < 25; ++i) {
    float4 v = *(const float4*)(base + (size_t)(i * 256 + tid) * 4);
    s += v.x + v.y + v.z + v.w;
    m = fmaxf(m, fmaxf(fmaxf(v.x, v.y), fmaxf(v.z, v.w)));
  }
  __shared__ float ss[256], sm[256];
  ss[tid] = s; sm[tid] = m;
  __syncthreads();
  for (int st = 128; st > 0; st >>= 1) {
    if (tid < st) { ss[tid] += ss[tid + st]; sm[tid] = fmaxf(sm[tid], sm[tid + st]); }
    __syncthreads();
  }
  if (tid == 0) { redavg[bid] = ss[0] * (1.0f / 25600.0f); redmax[bid] = sm[0]; }
}

// ---------------- K2: zero the pad cells of the p buffer ----------------
__global__ void k_padzero(unsigned short* __restrict__ p) {
  unsigned short* base = p + (size_t)blockIdx.x * PPS;
  for (int i = threadIdx.x; i < PPS; i += 256) {
    int row = i / PROW, col = i - row * PROW;
    if (row < 3 || row >= 163 || col < 8 || col >= 168) base[i] = 0;
  }
}

// ---------------- K3a: h1 = relu(W1 @ y + b1) ----------------
__global__ void k_mlp1(const float* __restrict__ redavg, const float* __restrict__ redmax,
                       const float* __restrict__ w1, const float* __restrict__ b1,
                       float* __restrict__ h1) {
  int b = blockIdx.y;
  __shared__ float ybuf[768];
  int tid = threadIdx.x;
  for (int i = tid; i < 768; i += 256)
    ybuf[i] = (i < CH2) ? redavg[b * CH2 + i] : redmax[b * CH2 + i - CH2];
  __syncthreads();
  int lane = tid & 63, wid = tid >> 6;
  int o0 = blockIdx.x * 256 + wid * 64;
  for (int oi = 0; oi < 64; ++oi) {
    int o = o0 + oi;
    const float* wr = w1 + (size_t)o * 768 + lane;
    float a = 0.f;
    #pragma unroll
    for (int j = 0; j < 12; ++j) a += wr[j * 64] * ybuf[lane + j * 64];
    #pragma unroll
    for (int k = 32; k >= 1; k >>= 1) a += __shfl_xor(a, k, 64);
    if (lane == 0) h1[b * 768 + o] = fmaxf(a + b1[o], 0.f);
  }
}

// ---------------- K3b: cw = sigmoid(W2 @ h1 + b2) ----------------
__global__ void k_mlp2(const float* __restrict__ h1, const float* __restrict__ w2,
                       const float* __restrict__ b2, float* __restrict__ cw) {
  int b = blockIdx.y;
  __shared__ float hbuf[768];
  int tid = threadIdx.x;
  for (int i = tid; i < 768; i += 256) hbuf[i] = h1[b * 768 + i];
  __syncthreads();
  int lane = tid & 63, wid = tid >> 6;
  int o0 = blockIdx.x * 256 + wid * 64;
  for (int oi = 0; oi < 64; ++oi) {
    int o = o0 + oi;
    if (o >= CH2) break;
    const float* wr = w2 + (size_t)o * 768 + lane;
    float a = 0.f;
    #pragma unroll
    for (int j = 0; j < 12; ++j) a += wr[j * 64] * hbuf[lane + j * 64];
    #pragma unroll
    for (int k = 32; k >= 1; k >>= 1) a += __shfl_xor(a, k, 64);
    if (lane == 0) cw[b * CH2 + o] = 1.f / (1.f + expf(-(a + b2[o])));
  }
}

// ---------------- K4: GEMM1  p[o][s] = sum_c w_in[o][c] * x[c][s] (bf16 MFMA) ----------------
#define G1_ST 72
__global__ __launch_bounds__(256, 2)
void k_gemm1(const float* __restrict__ x1, const float* __restrict__ x2,
             const float* __restrict__ w_in, unsigned short* __restrict__ p) {
  __shared__ short Alds[PCH * G1_ST];   // 288x64 chunk of w_in (bf16), stride 72
  __shared__ short Blds[128 * G1_ST];   // 128(s) x 64(c) of x, transposed, stride 72
  int tid = threadIdx.x;
  int b = blockIdx.y;
  int ns = blockIdx.x * 128;
  int lane = tid & 63, wid = tid >> 6;
  int quad = lane >> 4, l15 = lane & 15;
  int wm = wid >> 1, wn = wid & 1;

  f32x4 acc[9][4];
  #pragma unroll
  for (int i = 0; i < 9; ++i) {
    #pragma unroll
    for (int j = 0; j < 4; ++j) acc[i][j] = (f32x4){0.f, 0.f, 0.f, 0.f};
  }

  for (int kk = 0; kk < 6; ++kk) {
    int kc = kk * 64;
    __syncthreads();
    // stage A: w_in rows 0..287, cols kc..kc+63
    #pragma unroll
    for (int i = 0; i < 18; ++i) {
      int idx = i * 256 + tid;
      int row = idx >> 4, col4 = (idx & 15) << 2;
      float4 w4 = *(const float4*)(w_in + (size_t)row * CH2 + kc + col4);
      unsigned int lo = (unsigned int)f2bf(w4.x) | ((unsigned int)f2bf(w4.y) << 16);
      unsigned int hi = (unsigned int)f2bf(w4.z) | ((unsigned int)f2bf(w4.w) << 16);
      *(uint2*)&Alds[row * G1_ST + col4] = make_uint2(lo, hi);
    }
    // stage B: x[kc..kc+63][ns..ns+127] -> Blds[s][c] (4x4 micro-transpose)
    {
      const float* xb = (kc < DIM) ? (x1 + ((size_t)b * DIM + kc) * HW)
                                   : (x2 + ((size_t)b * DIM + (kc - DIM)) * HW);
      #pragma unroll
      for (int it = 0; it < 2; ++it) {
        int idx = it * 256 + tid;
        int sg = idx & 31, cg = idx >> 5;
        int c4 = cg << 2, s4 = sg << 2;
        const float* src = xb + (size_t)c4 * HW + ns + s4;
        float4 r0 = *(const float4*)(src);
        float4 r1 = *(const float4*)(src + HW);
        float4 r2 = *(const float4*)(src + 2 * HW);
        float4 r3 = *(const float4*)(src + 3 * HW);
        unsigned short t0[4] = {f2bf(r0.x), f2bf(r0.y), f2bf(r0.z), f2bf(r0.w)};
        unsigned short t1[4] = {f2bf(r1.x), f2bf(r1.y), f2bf(r1.z), f2bf(r1.w)};
        unsigned short t2[4] = {f2bf(r2.x), f2bf(r2.y), f2bf(r2.z), f2bf(r2.w)};
        unsigned short t3[4] = {f2bf(r3.x), f2bf(r3.y), f2bf(r3.z), f2bf(r3.w)};
        #pragma unroll
        for (int j = 0; j < 4; ++j) {
          unsigned int lo = (unsigned int)t0[j] | ((unsigned int)t1[j] << 16);
          unsigned int hi = (unsigned int)t2[j] | ((unsigned int)t3[j] << 16);
          *(uint2*)&Blds[(s4 + j) * G1_ST + c4] = make_uint2(lo, hi);
        }
      }
    }
    __syncthreads();
    #pragma unroll
    for (int ks = 0; ks < 2; ++ks) {
      int kof = ks * 32 + quad * 8;
      bf16x8 bfr[4];
      #pragma unroll
      for (int nt = 0; nt < 4; ++nt)
        bfr[nt] = *(const bf16x8*)&Blds[(wn * 64 + nt * 16 + l15) * G1_ST + kof];
      #pragma unroll
      for (int mt = 0; mt < 9; ++mt) {
        bf16x8 af = *(const bf16x8*)&Alds[(wm * 144 + mt * 16 + l15) * G1_ST + kof];
        #pragma unroll
        for (int nt = 0; nt < 4; ++nt)
          acc[mt][nt] = __builtin_amdgcn_mfma_f32_16x16x32_bf16(af, bfr[nt], acc[mt][nt], 0, 0, 0);
      }
    }
  }
  // epilogue: bf16 store into padded p
  unsigned short* pb = p + (size_t)b * PCH * PPS;
  #pragma unroll
  for (int mt = 0; mt < 9; ++mt) {
    int obase = wm * 144 + mt * 16 + quad * 4;
    #pragma unroll
    for (int nt = 0; nt < 4; ++nt) {
      int s = ns + wn * 64 + nt * 16 + l15;
      int yy = s / WIDTH;
      int xx = s - yy * WIDTH;
      #pragma unroll
      for (int r = 0; r < 4; ++r) {
        int o = obase + r;
        pb[(size_t)o * PPS + (size_t)(yy + 3) * PROW + xx + 8] = f2bf(acc[mt][nt][r]);
      }
    }
  }
}

// ---------------- K5: depthwise convs (dil 1/2/3) + GELU gate ----------------
__global__ void k_dwgelu(const unsigned short* __restrict__ p,
                         const float* __restrict__ wd1, const float* __restrict__ wd2,
                         const float* __restrict__ wd3, unsigned short* __restrict__ g) {
  int t = blockIdx.x * 256 + threadIdx.x;   // 614400 tasks: 8 cols x 4 rows each
  int cg = t % 20;
  int rest = t / 20;
  int rg = rest % 40;
  rest /= 40;
  int c = rest % 96;
  int b = rest / 96;
  int x0 = cg * 8, y0 = rg * 4;

  const unsigned short* pa = p + ((size_t)(b * PCH) + c) * PPS;
  const unsigned short* p2 = pa + (size_t)96 * PPS;
  const unsigned short* p3 = pa + (size_t)192 * PPS;

  float acc_a[4][8], acc_g[4][8];
  #pragma unroll
  for (int i = 0; i < 4; ++i) {
    #pragma unroll
    for (int j = 0; j < 8; ++j) { acc_a[i][j] = 0.f; acc_g[i][j] = 0.f; }
  }

  // plane a (dil 1): rows y0-1..y0+4, taps v[ox+kx+1], window starts x0-2
  {
    float w[9];
    #pragma unroll
    for (int i = 0; i < 9; ++i) w[i] = wd1[c * 9 + i];
    #pragma unroll
    for (int ri = 0; ri < 6; ++ri) {
      int r = y0 - 1 + ri;
      const unsigned int* rowp = (const unsigned int*)(pa + (size_t)(r + 3) * PROW + x0 + 6);
      float v[12];
      #pragma unroll
      for (int u = 0; u < 6; ++u) {
        unsigned int d = rowp[u];
        v[2 * u] = bf2f(d & 0xFFFFu);
        v[2 * u + 1] = bf2f(d >> 16);
      }
      #pragma unroll
      for (int ky = 0; ky < 3; ++ky) {
        int oy = ri - ky;
        if (oy >= 0 && oy < 4) {
          #pragma unroll
          for (int kx = 0; kx < 3; ++kx) {
            float wv = w[ky * 3 + kx];
            #pragma unroll
            for (int ox = 0; ox < 8; ++ox) acc_a[oy][ox] += wv * v[ox + kx + 1];
          }
        }
      }
    }
  }
  // plane g2 (dil 2): rows y0-2..y0+5, taps v[ox+2kx], window starts x0-2
  {
    float w[9];
    #pragma unroll
    for (int i = 0; i < 9; ++i) w[i] = wd2[c * 9 + i];
    #pragma unroll
    for (int ri = 0; ri < 8; ++ri) {
      int r = y0 - 2 + ri;
      const unsigned int* rowp = (const unsigned int*)(p2 + (size_t)(r + 3) * PROW + x0 + 6);
      float v[12];
      #pragma unroll
      for (int u = 0; u < 6; ++u) {
        unsigned int d = rowp[u];
        v[2 * u] = bf2f(d & 0xFFFFu);
        v[2 * u + 1] = bf2f(d >> 16);
      }
      #pragma unroll
      for (int ky = 0; ky < 3; ++ky) {
        int oy = ri - 2 * ky;
        if (oy >= 0 && oy < 4) {
          #pragma unroll
          for (int kx = 0; kx < 3; ++kx) {
            float wv = w[ky * 3 + kx];
            #pragma unroll
            for (int ox = 0; ox < 8; ++ox) acc_g[oy][ox] += wv * v[ox + 2 * kx];
          }
        }
      }
    }
  }
  // plane g3 (dil 3): rows y0-3..y0+6, taps v[ox+3kx+1], window starts x0-4
  {
    float w[9];
    #pragma unroll
    for (int i = 0; i < 9; ++i) w[i] = wd3[c * 9 + i];
    #pragma unroll
    for (int ri = 0; ri < 10; ++ri) {
      int r = y0 - 3 + ri;
      const unsigned int* rowp = (const unsigned int*)(p3 + (size_t)(r + 3) * PROW + x0 + 4);
      float v[16];
      #pragma unroll
      for (int u = 0; u < 8; ++u) {
        unsigned int d = rowp[u];
        v[2 * u] = bf2f(d & 0xFFFFu);
        v[2 * u + 1] = bf2f(d >> 16);
      }
      #pragma unroll
      for (int ky = 0; ky < 3; ++ky) {
        int oy = ri - 3 * ky;
        if (oy >= 0 && oy < 4) {
          #pragma unroll
          for (int kx = 0; kx < 3; ++kx) {
            float wv = w[ky * 3 + kx];
            #pragma unroll
            for (int ox = 0; ox < 8; ++ox) acc_g[oy][ox] += wv * v[ox + 3 * kx + 1];
          }
        }
      }
    }
  }

  unsigned short* gp = g + ((size_t)(b * 96) + c) * HW;
  #pragma unroll
  for (int oy = 0; oy < 4; ++oy) {
    unsigned int out4[4];
    #pragma unroll
    for (int j = 0; j < 4; ++j) {
      float a0 = acc_a[oy][2 * j], a1 = acc_a[oy][2 * j + 1];
      float g0 = 0.5f * a0 * (1.f + erff(a0 * 0.70710678118f)) * acc_g[oy][2 * j];
      float g1 = 0.5f * a1 * (1.f + erff(a1 * 0.70710678118f)) * acc_g[oy][2 * j + 1];
      out4[j] = (unsigned int)f2bf(g0) | ((unsigned int)f2bf(g1) << 16);
    }
    *(uint4*)&gp[(size_t)(y0 + oy) * WIDTH + x0] = make_uint4(out4[0], out4[1], out4[2], out4[3]);
  }
}

// ---------------- K6: GEMM2 (96->384) + residual/channel-weight fuse ----------------
#define G2_ST 104
__global__ __launch_bounds__(256, 2)
void k_gemm2(const unsigned short* __restrict__ g, const float* __restrict__ w_out,
             const float* __restrict__ x1, const float* __restrict__ x2,
             const float* __restrict__ cw, float* __restrict__ out) {
  __shared__ short Alds[128 * G2_ST];
  __shared__ short Blds[128 * G2_ST];
  int tid = threadIdx.x;
  int ns = blockIdx.x * 128;
  int mo = blockIdx.y * 128;
  int b = blockIdx.z;
  int lane = tid & 63, wid = tid >> 6;
  int quad = lane >> 4, l15 = lane & 15;
  int wm = wid >> 1, wn = wid & 1;

  // stage A: w_out[mo..mo+127][0..95]
  #pragma unroll
  for (int i = 0; i < 12; ++i) {
    int idx = i * 256 + tid;               // 0..3071 float4 groups
    int row = idx / 24, c4 = (idx % 24) * 4;
    float4 w4 = *(const float4*)(w_out + (size_t)(mo + row) * HID + c4);
    unsigned int lo = (unsigned int)f2bf(w4.x) | ((unsigned int)f2bf(w4.y) << 16);
    unsigned int hi = (unsigned int)f2bf(w4.z) | ((unsigned int)f2bf(w4.w) << 16);
    *(uint2*)&Alds[row * G2_ST + c4] = make_uint2(lo, hi);
  }
  // stage B: g[0..95][ns..ns+127] transposed into Blds[s][c]
  const unsigned short* gb = g + (size_t)b * HID * HW;
  #pragma unroll
  for (int it = 0; it < 3; ++it) {
    int idx = it * 256 + tid;              // 0..767 micro tiles
    int sg = idx & 31, cg = idx >> 5;      // cg 0..23
    int c4 = cg * 4, s4 = sg * 4;
    const unsigned short* src = gb + (size_t)c4 * HW + ns + s4;
    uint2 r0 = *(const uint2*)(src);
    uint2 r1 = *(const uint2*)(src + HW);
    uint2 r2 = *(const uint2*)(src + 2 * HW);
    uint2 r3 = *(const uint2*)(src + 3 * HW);
    unsigned short e0[4] = {(unsigned short)r0.x, (unsigned short)(r0.x >> 16), (unsigned short)r0.y, (unsigned short)(r0.y >> 16)};
    unsigned short e1[4] = {(unsigned short)r1.x, (unsigned short)(r1.x >> 16), (unsigned short)r1.y, (unsigned short)(r1.y >> 16)};
    unsigned short e2[4] = {(unsigned short)r2.x, (unsigned short)(r2.x >> 16), (unsigned short)r2.y, (unsigned short)(r2.y >> 16)};
    unsigned short e3[4] = {(unsigned short)r3.x, (unsigned short)(r3.x >> 16), (unsigned short)r3.y, (unsigned short)(r3.y >> 16)};
    #pragma unroll
    for (int j = 0; j < 4; ++j) {
      unsigned int lo = (unsigned int)e0[j] | ((unsigned int)e1[j] << 16);
      unsigned int hi = (unsigned int)e2[j] | ((unsigned int)e3[j] << 16);
      *(uint2*)&Blds[(s4 + j) * G2_ST + c4] = make_uint2(lo, hi);
    }
  }
  __syncthreads();

  f32x4 acc[4][4];
  #pragma unroll
  for (int i = 0; i < 4; ++i) {
    #pragma unroll
    for (int j = 0; j < 4; ++j) acc[i][j] = (f32x4){0.f, 0.f, 0.f, 0.f};
  }
  #pragma unroll
  for (int ks = 0; ks < 3; ++ks) {
    int kof = ks * 32 + quad * 8;
    bf16x8 bfr[4];
    #pragma unroll
    for (int nt = 0; nt < 4; ++nt)
      bfr[nt] = *(const bf16x8*)&Blds[(wn * 64 + nt * 16 + l15) * G2_ST + kof];
    #pragma unroll
    for (int mt = 0; mt < 4; ++mt) {
      bf16x8 af = *(const bf16x8*)&Alds[(wm * 64 + mt * 16 + l15) * G2_ST + kof];
      #pragma unroll
      for (int nt = 0; nt < 4; ++nt)
        acc[mt][nt] = __builtin_amdgcn_mfma_f32_16x16x32_bf16(af, bfr[nt], acc[mt][nt], 0, 0, 0);
    }
  }

  const float* cwb = cw + b * CH2;
  #pragma unroll
  for (int mt = 0; mt < 4; ++mt) {
    int o2b = mo + wm * 64 + mt * 16 + quad * 4;
    #pragma unroll
    for (int nt = 0; nt < 4; ++nt) {
      int s = ns + wn * 64 + nt * 16 + l15;
      #pragma unroll
      for (int r = 0; r < 4; ++r) {
        int o2 = o2b + r;
        int cch = (o2 < DIM) ? o2 : (o2 - DIM);
        size_t coff = ((size_t)b * DIM + cch) * HW + s;
        float v1 = x1[coff], v2 = x2[coff];
        float cwv = cwb[o2];
        float swv = acc[mt][nt][r];
        if (o2 < DIM) {
          out[OUTN + coff] = v2 + 0.5f * cwv * v1 + 0.5f * swv;   // out_x2
        } else {
          out[coff] = v1 + 0.5f * cwv * v2 + 0.5f * swv;          // out_x1
        }
      }
    }
  }
}

extern "C" void kernel_launch(void* const* d_in, const int* in_sizes, int n_in,
                              void* d_out, int out_size, void* d_ws, size_t ws_size,
                              hipStream_t stream) {
  const float* x1 = (const float*)d_in[0];
  const float* x2 = (const float*)d_in[1];
  const float* mlp_w1 = (const float*)d_in[2];
  const float* mlp_b1 = (const float*)d_in[3];
  const float* mlp_w2 = (const float*)d_in[4];
  const float* mlp_b2 = (const float*)d_in[5];
  const float* w_in = (const float*)d_in[6];
  const float* w_dw1 = (const float*)d_in[7];
  const float* w_dw2 = (const float*)d_in[8];
  const float* w_dw3 = (const float*)d_in[9];
  const float* w_out = (const float*)d_in[10];
  float* out = (float*)d_out;

  char* ws = (char*)d_ws;
  float* redavg = (float*)(ws + 0);                 // 3072 f
  float* redmax = (float*)(ws + 12288);             // 3072 f
  float* h1     = (float*)(ws + 24576);             // 6144 f
  float* cw     = (float*)(ws + 49152);             // 3072 f
  unsigned short* p = (unsigned short*)(ws + 65536);             // 8*288*29216 bf16
  unsigned short* g = (unsigned short*)(ws + 65536 + 134627328); // 8*96*25600 bf16

  k_reduce <<<dim3(3072),        dim3(256), 0, stream>>>(x1, x2, redavg, redmax);
  k_padzero<<<dim3(2304),        dim3(256), 0, stream>>>(p);
  k_mlp1   <<<dim3(3, 8),        dim3(256), 0, stream>>>(redavg, redmax, mlp_w1, mlp_b1, h1);
  k_mlp2   <<<dim3(2, 8),        dim3(256), 0, stream>>>(h1, mlp_w2, mlp_b2, cw);
  k_gemm1  <<<dim3(200, 8),      dim3(256), 0, stream>>>(x1, x2, w_in, p);
  k_dwgelu <<<dim3(2400),        dim3(256), 0, stream>>>(p, w_dw1, w_dw2, w_dw3, g);
  k_gemm2  <<<dim3(200, 3, 8),   dim3(256), 0, stream>>>(g, w_out, x1, x2, cw, out);
}

// Round 2
// 1300.164 us; speedup vs baseline: 1.2199x; 1.2199x over previous
//
#include <hip/hip_runtime.h>
#include <cstdint>

#define HW 25600
#define WIDTH 160
#define NB 8
#define DIM 192
#define CH2 384
#define PCH 288
#define HID 96
#define PROW 176
#define PPS 29216          // 166*176 padded plane (shorts)
#define OUTN 39321600      // 8*192*25600

typedef short bf16x8 __attribute__((ext_vector_type(8)));
typedef float f32x4 __attribute__((ext_vector_type(4)));

__device__ __forceinline__ unsigned short f2bf(float f) {
  union { float f; unsigned int u; } v; v.f = f;
  unsigned int u = v.u;
  u += 0x7FFFu + ((u >> 16) & 1u);
  return (unsigned short)(u >> 16);
}
__device__ __forceinline__ float bf2f(unsigned int bits16) {
  union { unsigned int u; float f; } v; v.u = bits16 << 16;
  return v.f;
}
// monotone float<->uint key for atomicMax on floats
__device__ __forceinline__ unsigned fkey(float f) {
  int i = __float_as_int(f);
  return (i >= 0) ? ((unsigned)i | 0x80000000u) : ~(unsigned)i;
}
__device__ __forceinline__ float funkey(unsigned u) {
  int i = (u & 0x80000000u) ? (int)(u & 0x7FFFFFFFu) : ~(int)u;
  return __int_as_float(i);
}

// ---------------- K0: init reduction buffers (ws is poisoned each call) ----------------
__global__ void k_init(float* __restrict__ redsum, unsigned* __restrict__ redmaxu) {
  int i = blockIdx.x * 256 + threadIdx.x;
  if (i < NB * CH2) { redsum[i] = 0.f; redmaxu[i] = 0x007FFFFFu; }  // key(-inf)
}

// ---------------- K2: zero only the pad cells of the p buffer ----------------
__global__ void k_padzero(unsigned short* __restrict__ p) {
  unsigned short* base = p + (size_t)blockIdx.x * PPS;
  for (int i = threadIdx.x; i < 3616; i += 256) {
    int row, col;
    if (i < 1056) {               // 6 full pad rows (0,1,2,163,164,165)
      int r = i / PROW; col = i - r * PROW;
      row = (r < 3) ? r : 160 + r;
    } else {                      // 16 pad cols for the 160 interior rows
      int j = i - 1056;
      int r = j >> 4, cc = j & 15;
      row = 3 + r;
      col = (cc < 8) ? cc : 160 + cc;
    }
    base[row * PROW + col] = 0;
  }
}

// ---------------- K3a: h1 = relu(W1 @ y + b1) ----------------
__global__ void k_mlp1(const float* __restrict__ redsum, const unsigned* __restrict__ redmaxu,
                       const float* __restrict__ w1, const float* __restrict__ b1,
                       float* __restrict__ h1) {
  int b = blockIdx.y;
  __shared__ float ybuf[768];
  int tid = threadIdx.x;
  for (int i = tid; i < 768; i += 256)
    ybuf[i] = (i < CH2) ? redsum[b * CH2 + i] * (1.0f / 25600.0f)
                        : funkey(redmaxu[b * CH2 + i - CH2]);
  __syncthreads();
  int lane = tid & 63, wid = tid >> 6;
  int o0 = blockIdx.x * 256 + wid * 64;
  for (int oi = 0; oi < 64; ++oi) {
    int o = o0 + oi;
    const float* wr = w1 + (size_t)o * 768 + lane;
    float a = 0.f;
    #pragma unroll
    for (int j = 0; j < 12; ++j) a += wr[j * 64] * ybuf[lane + j * 64];
    #pragma unroll
    for (int k = 32; k >= 1; k >>= 1) a += __shfl_xor(a, k, 64);
    if (lane == 0) h1[b * 768 + o] = fmaxf(a + b1[o], 0.f);
  }
}

// ---------------- K3b: cw = sigmoid(W2 @ h1 + b2) ----------------
__global__ void k_mlp2(const float* __restrict__ h1, const float* __restrict__ w2,
                       const float* __restrict__ b2, float* __restrict__ cw) {
  int b = blockIdx.y;
  __shared__ float hbuf[768];
  int tid = threadIdx.x;
  for (int i = tid; i < 768; i += 256) hbuf[i] = h1[b * 768 + i];
  __syncthreads();
  int lane = tid & 63, wid = tid >> 6;
  int o0 = blockIdx.x * 256 + wid * 64;
  for (int oi = 0; oi < 64; ++oi) {
    int o = o0 + oi;
    if (o >= CH2) break;
    const float* wr = w2 + (size_t)o * 768 + lane;
    float a = 0.f;
    #pragma unroll
    for (int j = 0; j < 12; ++j) a += wr[j * 64] * hbuf[lane + j * 64];
    #pragma unroll
    for (int k = 32; k >= 1; k >>= 1) a += __shfl_xor(a, k, 64);
    if (lane == 0) cw[b * CH2 + o] = 1.f / (1.f + expf(-(a + b2[o])));
  }
}

// ---------------- K4: GEMM1 + fused global avg/max reduction ----------------
#define G1_ST 72
__global__ __launch_bounds__(256, 2)
void k_gemm1(const float* __restrict__ x1, const float* __restrict__ x2,
             const float* __restrict__ w_in, unsigned short* __restrict__ p,
             float* __restrict__ redsum, unsigned* __restrict__ redmaxu) {
  __shared__ short Alds[PCH * G1_ST];   // 288x64 chunk of w_in (bf16), stride 72
  __shared__ short Blds[128 * G1_ST];   // 128(s) x 64(c) of x, transposed, stride 72
  int tid = threadIdx.x;
  int b = blockIdx.y;
  int ns = blockIdx.x * 128;
  int lane = tid & 63, wid = tid >> 6;
  int quad = lane >> 4, l15 = lane & 15;
  int wm = wid >> 1, wn = wid & 1;

  f32x4 acc[9][4];
  #pragma unroll
  for (int i = 0; i < 9; ++i) {
    #pragma unroll
    for (int j = 0; j < 4; ++j) acc[i][j] = (f32x4){0.f, 0.f, 0.f, 0.f};
  }

  for (int kk = 0; kk < 6; ++kk) {
    int kc = kk * 64;
    __syncthreads();
    // stage A: w_in rows 0..287, cols kc..kc+63
    #pragma unroll
    for (int i = 0; i < 18; ++i) {
      int idx = i * 256 + tid;
      int row = idx >> 4, col4 = (idx & 15) << 2;
      float4 w4 = *(const float4*)(w_in + (size_t)row * CH2 + kc + col4);
      unsigned int lo = (unsigned int)f2bf(w4.x) | ((unsigned int)f2bf(w4.y) << 16);
      unsigned int hi = (unsigned int)f2bf(w4.z) | ((unsigned int)f2bf(w4.w) << 16);
      *(uint2*)&Alds[row * G1_ST + col4] = make_uint2(lo, hi);
    }
    // stage B: x[kc..kc+63][ns..ns+127] -> Blds[s][c] (4x4 micro-transpose)
    {
      const float* xb = (kc < DIM) ? (x1 + ((size_t)b * DIM + kc) * HW)
                                   : (x2 + ((size_t)b * DIM + (kc - DIM)) * HW);
      #pragma unroll
      for (int it = 0; it < 2; ++it) {
        int idx = it * 256 + tid;
        int sg = idx & 31, cg = idx >> 5;
        int c4 = cg << 2, s4 = sg << 2;
        const float* src = xb + (size_t)c4 * HW + ns + s4;
        float4 r0 = *(const float4*)(src);
        float4 r1 = *(const float4*)(src + HW);
        float4 r2 = *(const float4*)(src + 2 * HW);
        float4 r3 = *(const float4*)(src + 3 * HW);
        // ---- fused avg/max reduction over x (each element visited once) ----
        float s0 = r0.x + r0.y + r0.z + r0.w;
        float s1 = r1.x + r1.y + r1.z + r1.w;
        float s2 = r2.x + r2.y + r2.z + r2.w;
        float s3 = r3.x + r3.y + r3.z + r3.w;
        float m0 = fmaxf(fmaxf(r0.x, r0.y), fmaxf(r0.z, r0.w));
        float m1 = fmaxf(fmaxf(r1.x, r1.y), fmaxf(r1.z, r1.w));
        float m2 = fmaxf(fmaxf(r2.x, r2.y), fmaxf(r2.z, r2.w));
        float m3 = fmaxf(fmaxf(r3.x, r3.y), fmaxf(r3.z, r3.w));
        #pragma unroll
        for (int msk = 16; msk >= 1; msk >>= 1) {
          s0 += __shfl_xor(s0, msk, 64);
          s1 += __shfl_xor(s1, msk, 64);
          s2 += __shfl_xor(s2, msk, 64);
          s3 += __shfl_xor(s3, msk, 64);
          m0 = fmaxf(m0, __shfl_xor(m0, msk, 64));
          m1 = fmaxf(m1, __shfl_xor(m1, msk, 64));
          m2 = fmaxf(m2, __shfl_xor(m2, msk, 64));
          m3 = fmaxf(m3, __shfl_xor(m3, msk, 64));
        }
        if ((tid & 31) == 0) {
          int ch = kc + c4;
          float* rs = redsum + b * CH2 + ch;
          atomicAdd(rs + 0, s0);
          atomicAdd(rs + 1, s1);
          atomicAdd(rs + 2, s2);
          atomicAdd(rs + 3, s3);
          unsigned* rm = redmaxu + b * CH2 + ch;
          atomicMax(rm + 0, fkey(m0));
          atomicMax(rm + 1, fkey(m1));
          atomicMax(rm + 2, fkey(m2));
          atomicMax(rm + 3, fkey(m3));
        }
        // ---- bf16 transpose into LDS ----
        unsigned short t0[4] = {f2bf(r0.x), f2bf(r0.y), f2bf(r0.z), f2bf(r0.w)};
        unsigned short t1[4] = {f2bf(r1.x), f2bf(r1.y), f2bf(r1.z), f2bf(r1.w)};
        unsigned short t2[4] = {f2bf(r2.x), f2bf(r2.y), f2bf(r2.z), f2bf(r2.w)};
        unsigned short t3[4] = {f2bf(r3.x), f2bf(r3.y), f2bf(r3.z), f2bf(r3.w)};
        #pragma unroll
        for (int j = 0; j < 4; ++j) {
          unsigned int lo = (unsigned int)t0[j] | ((unsigned int)t1[j] << 16);
          unsigned int hi = (unsigned int)t2[j] | ((unsigned int)t3[j] << 16);
          *(uint2*)&Blds[(s4 + j) * G1_ST + c4] = make_uint2(lo, hi);
        }
      }
    }
    __syncthreads();
    #pragma unroll
    for (int ks = 0; ks < 2; ++ks) {
      int kof = ks * 32 + quad * 8;
      bf16x8 bfr[4];
      #pragma unroll
      for (int nt = 0; nt < 4; ++nt)
        bfr[nt] = *(const bf16x8*)&Blds[(wn * 64 + nt * 16 + l15) * G1_ST + kof];
      #pragma unroll
      for (int mt = 0; mt < 9; ++mt) {
        bf16x8 af = *(const bf16x8*)&Alds[(wm * 144 + mt * 16 + l15) * G1_ST + kof];
        #pragma unroll
        for (int nt = 0; nt < 4; ++nt)
          acc[mt][nt] = __builtin_amdgcn_mfma_f32_16x16x32_bf16(af, bfr[nt], acc[mt][nt], 0, 0, 0);
      }
    }
  }
  // epilogue: bf16 store into padded p
  unsigned short* pb = p + (size_t)b * PCH * PPS;
  #pragma unroll
  for (int mt = 0; mt < 9; ++mt) {
    int obase = wm * 144 + mt * 16 + quad * 4;
    #pragma unroll
    for (int nt = 0; nt < 4; ++nt) {
      int s = ns + wn * 64 + nt * 16 + l15;
      int yy = s / WIDTH;
      int xx = s - yy * WIDTH;
      #pragma unroll
      for (int r = 0; r < 4; ++r) {
        int o = obase + r;
        pb[(size_t)o * PPS + (size_t)(yy + 3) * PROW + xx + 8] = f2bf(acc[mt][nt][r]);
      }
    }
  }
}

// ---------------- K5: depthwise convs (dil 1/2/3) + GELU gate, LDS-tiled ----------------
// Block: one (b,c), 160x16 tile. LDS stages halo'd row bands of the 3 planes.
#define TH 16
__global__ __launch_bounds__(256)
void k_dwgelu(const unsigned short* __restrict__ p,
              const float* __restrict__ wd1, const float* __restrict__ wd2,
              const float* __restrict__ wd3, unsigned short* __restrict__ g) {
  __shared__ unsigned lds[(18 + 20 + 22) * 88];   // 21120 B
  unsigned* la = lds;                // 18 rows (global y0-1 .. y0+16)
  unsigned* l2 = lds + 18 * 88;      // 20 rows (y0-2 .. y0+17)
  unsigned* l3 = lds + 38 * 88;      // 22 rows (y0-3 .. y0+18)

  int rg = blockIdx.x, c = blockIdx.y, b = blockIdx.z;
  int y0 = rg * TH;
  int tid = threadIdx.x;

  const unsigned short* pa = p + ((size_t)(b * PCH) + c) * PPS;
  const unsigned* srcA = (const unsigned*)(pa + (size_t)(y0 + 2) * PROW);
  const unsigned* src2 = (const unsigned*)(pa + (size_t)96 * PPS + (size_t)(y0 + 1) * PROW);
  const unsigned* src3 = (const unsigned*)(pa + (size_t)192 * PPS + (size_t)y0 * PROW);
  for (int i = tid; i < 18 * 88; i += 256) la[i] = srcA[i];
  for (int i = tid; i < 20 * 88; i += 256) l2[i] = src2[i];
  for (int i = tid; i < 22 * 88; i += 256) l3[i] = src3[i];

  float w1r[9], w2r[9], w3r[9];
  #pragma unroll
  for (int i = 0; i < 9; ++i) { w1r[i] = wd1[c * 9 + i]; w2r[i] = wd2[c * 9 + i]; w3r[i] = wd3[c * 9 + i]; }
  __syncthreads();

  int oy = tid >> 4;            // 0..15
  int cg = tid & 15;
  int ox0 = cg * 10;            // 0..150
  int ub = 3 + (ox0 >> 1);      // uint col base for a/g2 (px col 6+ox0)
  int ub3 = 2 + (ox0 >> 1);     // uint col base for g3  (px col 4+ox0)

  float acc_a[10], acc_g[10];
  #pragma unroll
  for (int i = 0; i < 10; ++i) { acc_a[i] = 0.f; acc_g[i] = 0.f; }

  // plane a (dil 1): rows oy+ky in la; tap vindex = oxi+kx+1
  #pragma unroll
  for (int ky = 0; ky < 3; ++ky) {
    const unsigned* rp = la + (oy + ky) * 88 + ub;
    float v[14];
    #pragma unroll
    for (int u = 0; u < 7; ++u) { unsigned d = rp[u]; v[2 * u] = bf2f(d & 0xFFFFu); v[2 * u + 1] = bf2f(d >> 16); }
    #pragma unroll
    for (int kx = 0; kx < 3; ++kx) {
      float wv = w1r[ky * 3 + kx];
      #pragma unroll
      for (int i = 0; i < 10; ++i) acc_a[i] += wv * v[i + kx + 1];
    }
  }
  // plane g2 (dil 2): rows oy+2ky in l2; tap vindex = oxi+2kx
  #pragma unroll
  for (int ky = 0; ky < 3; ++ky) {
    const unsigned* rp = l2 + (oy + 2 * ky) * 88 + ub;
    float v[14];
    #pragma unroll
    for (int u = 0; u < 7; ++u) { unsigned d = rp[u]; v[2 * u] = bf2f(d & 0xFFFFu); v[2 * u + 1] = bf2f(d >> 16); }
    #pragma unroll
    for (int kx = 0; kx < 3; ++kx) {
      float wv = w2r[ky * 3 + kx];
      #pragma unroll
      for (int i = 0; i < 10; ++i) acc_g[i] += wv * v[i + 2 * kx];
    }
  }
  // plane g3 (dil 3): rows oy+3ky in l3; tap vindex = oxi+3kx+1
  #pragma unroll
  for (int ky = 0; ky < 3; ++ky) {
    const unsigned* rp = l3 + (oy + 3 * ky) * 88 + ub3;
    float v[18];
    #pragma unroll
    for (int u = 0; u < 9; ++u) { unsigned d = rp[u]; v[2 * u] = bf2f(d & 0xFFFFu); v[2 * u + 1] = bf2f(d >> 16); }
    #pragma unroll
    for (int kx = 0; kx < 3; ++kx) {
      float wv = w3r[ky * 3 + kx];
      #pragma unroll
      for (int i = 0; i < 10; ++i) acc_g[i] += wv * v[i + 3 * kx + 1];
    }
  }

  unsigned short* gp = g + ((size_t)(b * HID) + c) * HW + (size_t)(y0 + oy) * WIDTH + ox0;
  #pragma unroll
  for (int j = 0; j < 5; ++j) {
    float a0 = acc_a[2 * j], a1 = acc_a[2 * j + 1];
    float g0 = 0.5f * a0 * (1.f + erff(a0 * 0.70710678118f)) * acc_g[2 * j];
    float g1 = 0.5f * a1 * (1.f + erff(a1 * 0.70710678118f)) * acc_g[2 * j + 1];
    ((unsigned*)gp)[j] = (unsigned)f2bf(g0) | ((unsigned)f2bf(g1) << 16);
  }
}

// ---------------- K6: GEMM2 (96->384) + residual/channel-weight fuse ----------------
#define G2_ST 104
__global__ __launch_bounds__(256, 2)
void k_gemm2(const unsigned short* __restrict__ g, const float* __restrict__ w_out,
             const float* __restrict__ x1, const float* __restrict__ x2,
             const float* __restrict__ cw, float* __restrict__ out) {
  __shared__ short Alds[128 * G2_ST];
  __shared__ short Blds[128 * G2_ST];
  int tid = threadIdx.x;
  int ns = blockIdx.x * 128;
  int mo = blockIdx.y * 128;
  int b = blockIdx.z;
  int lane = tid & 63, wid = tid >> 6;
  int quad = lane >> 4, l15 = lane & 15;
  int wm = wid >> 1, wn = wid & 1;

  // stage A: w_out[mo..mo+127][0..95]
  #pragma unroll
  for (int i = 0; i < 12; ++i) {
    int idx = i * 256 + tid;               // 0..3071 float4 groups
    int row = idx / 24, c4 = (idx % 24) * 4;
    float4 w4 = *(const float4*)(w_out + (size_t)(mo + row) * HID + c4);
    unsigned int lo = (unsigned int)f2bf(w4.x) | ((unsigned int)f2bf(w4.y) << 16);
    unsigned int hi = (unsigned int)f2bf(w4.z) | ((unsigned int)f2bf(w4.w) << 16);
    *(uint2*)&Alds[row * G2_ST + c4] = make_uint2(lo, hi);
  }
  // stage B: g[0..95][ns..ns+127] transposed into Blds[s][c]
  const unsigned short* gb = g + (size_t)b * HID * HW;
  #pragma unroll
  for (int it = 0; it < 3; ++it) {
    int idx = it * 256 + tid;              // 0..767 micro tiles
    int sg = idx & 31, cg = idx >> 5;      // cg 0..23
    int c4 = cg * 4, s4 = sg * 4;
    const unsigned short* src = gb + (size_t)c4 * HW + ns + s4;
    uint2 r0 = *(const uint2*)(src);
    uint2 r1 = *(const uint2*)(src + HW);
    uint2 r2 = *(const uint2*)(src + 2 * HW);
    uint2 r3 = *(const uint2*)(src + 3 * HW);
    unsigned short e0[4] = {(unsigned short)r0.x, (unsigned short)(r0.x >> 16), (unsigned short)r0.y, (unsigned short)(r0.y >> 16)};
    unsigned short e1[4] = {(unsigned short)r1.x, (unsigned short)(r1.x >> 16), (unsigned short)r1.y, (unsigned short)(r1.y >> 16)};
    unsigned short e2[4] = {(unsigned short)r2.x, (unsigned short)(r2.x >> 16), (unsigned short)r2.y, (unsigned short)(r2.y >> 16)};
    unsigned short e3[4] = {(unsigned short)r3.x, (unsigned short)(r3.x >> 16), (unsigned short)r3.y, (unsigned short)(r3.y >> 16)};
    #pragma unroll
    for (int j = 0; j < 4; ++j) {
      unsigned int lo = (unsigned int)e0[j] | ((unsigned int)e1[j] << 16);
      unsigned int hi = (unsigned int)e2[j] | ((unsigned int)e3[j] << 16);
      *(uint2*)&Blds[(s4 + j) * G2_ST + c4] = make_uint2(lo, hi);
    }
  }
  __syncthreads();

  f32x4 acc[4][4];
  #pragma unroll
  for (int i = 0; i < 4; ++i) {
    #pragma unroll
    for (int j = 0; j < 4; ++j) acc[i][j] = (f32x4){0.f, 0.f, 0.f, 0.f};
  }
  #pragma unroll
  for (int ks = 0; ks < 3; ++ks) {
    int kof = ks * 32 + quad * 8;
    bf16x8 bfr[4];
    #pragma unroll
    for (int nt = 0; nt < 4; ++nt)
      bfr[nt] = *(const bf16x8*)&Blds[(wn * 64 + nt * 16 + l15) * G2_ST + kof];
    #pragma unroll
    for (int mt = 0; mt < 4; ++mt) {
      bf16x8 af = *(const bf16x8*)&Alds[(wm * 64 + mt * 16 + l15) * G2_ST + kof];
      #pragma unroll
      for (int nt = 0; nt < 4; ++nt)
        acc[mt][nt] = __builtin_amdgcn_mfma_f32_16x16x32_bf16(af, bfr[nt], acc[mt][nt], 0, 0, 0);
    }
  }

  const float* cwb = cw + b * CH2;
  #pragma unroll
  for (int mt = 0; mt < 4; ++mt) {
    int o2b = mo + wm * 64 + mt * 16 + quad * 4;
    #pragma unroll
    for (int nt = 0; nt < 4; ++nt) {
      int s = ns + wn * 64 + nt * 16 + l15;
      #pragma unroll
      for (int r = 0; r < 4; ++r) {
        int o2 = o2b + r;
        int cch = (o2 < DIM) ? o2 : (o2 - DIM);
        size_t coff = ((size_t)b * DIM + cch) * HW + s;
        float v1 = x1[coff], v2 = x2[coff];
        float cwv = cwb[o2];
        float swv = acc[mt][nt][r];
        if (o2 < DIM) {
          out[OUTN + coff] = v2 + 0.5f * cwv * v1 + 0.5f * swv;   // out_x2
        } else {
          out[coff] = v1 + 0.5f * cwv * v2 + 0.5f * swv;          // out_x1
        }
      }
    }
  }
}

extern "C" void kernel_launch(void* const* d_in, const int* in_sizes, int n_in,
                              void* d_out, int out_size, void* d_ws, size_t ws_size,
                              hipStream_t stream) {
  const float* x1 = (const float*)d_in[0];
  const float* x2 = (const float*)d_in[1];
  const float* mlp_w1 = (const float*)d_in[2];
  const float* mlp_b1 = (const float*)d_in[3];
  const float* mlp_w2 = (const float*)d_in[4];
  const float* mlp_b2 = (const float*)d_in[5];
  const float* w_in = (const float*)d_in[6];
  const float* w_dw1 = (const float*)d_in[7];
  const float* w_dw2 = (const float*)d_in[8];
  const float* w_dw3 = (const float*)d_in[9];
  const float* w_out = (const float*)d_in[10];
  float* out = (float*)d_out;

  char* ws = (char*)d_ws;
  float* redsum       = (float*)(ws + 0);           // 3072 f
  unsigned* redmaxu   = (unsigned*)(ws + 12288);    // 3072 u (monotone keys)
  float* h1           = (float*)(ws + 24576);       // 6144 f
  float* cw           = (float*)(ws + 49152);       // 3072 f
  unsigned short* p = (unsigned short*)(ws + 65536);             // 8*288*29216 bf16
  unsigned short* g = (unsigned short*)(ws + 65536 + 134627328); // 8*96*25600 bf16

  k_init   <<<dim3(12),          dim3(256), 0, stream>>>(redsum, redmaxu);
  k_padzero<<<dim3(2304),        dim3(256), 0, stream>>>(p);
  k_gemm1  <<<dim3(200, 8),      dim3(256), 0, stream>>>(x1, x2, w_in, p, redsum, redmaxu);
  k_mlp1   <<<dim3(3, 8),        dim3(256), 0, stream>>>(redsum, redmaxu, mlp_w1, mlp_b1, h1);
  k_mlp2   <<<dim3(2, 8),        dim3(256), 0, stream>>>(h1, mlp_w2, mlp_b2, cw);
  k_dwgelu <<<dim3(10, 96, 8),   dim3(256), 0, stream>>>(p, w_dw1, w_dw2, w_dw3, g);
  k_gemm2  <<<dim3(200, 3, 8),   dim3(256), 0, stream>>>(g, w_out, x1, x2, cw, out);
}